// Round 1
// baseline (468.864 us; speedup 1.0000x reference)
//
#include <hip/hip_runtime.h>

typedef __bf16 bf16;
typedef bf16 bf16x8 __attribute__((ext_vector_type(8)));
typedef bf16 bf16x4 __attribute__((ext_vector_type(4)));
typedef float f32x4 __attribute__((ext_vector_type(4)));

#define MFMA16(a,b,c) __builtin_amdgcn_mfma_f32_16x16x32_bf16(a,b,c,0,0,0)

#define NSEQ 3136
#define CDIM 192

__device__ inline bf16x8 cvt8(float4 a, float4 b) {
  bf16x8 r;
  r[0]=(bf16)a.x; r[1]=(bf16)a.y; r[2]=(bf16)a.z; r[3]=(bf16)a.w;
  r[4]=(bf16)b.x; r[5]=(bf16)b.y; r[6]=(bf16)b.z; r[7]=(bf16)b.w;
  return r;
}

// ---------------- weight conversion fp32 -> bf16 ----------------
__global__ void k_convert(const float* __restrict__ qkv_w, const float* __restrict__ E_w,
                          const float* __restrict__ F_w, const float* __restrict__ proj_w,
                          bf16* __restrict__ qkvw, bf16* __restrict__ EF, bf16* __restrict__ projw) {
  int i = blockIdx.x * blockDim.x + threadIdx.x;
  const int tot = 950272;
  for (; i < tot; i += gridDim.x * blockDim.x) {
    if (i < 110592) qkvw[i] = (bf16)qkv_w[i];
    else if (i < 512000) EF[i - 110592] = (bf16)E_w[i - 110592];
    else if (i < 913408) EF[i - 110592] = (bf16)F_w[i - 512000];
    else projw[i - 913408] = (bf16)proj_w[i - 913408];
  }
}

// rowsums[kr] = sum_n E_w[kr,n] (kr<128) or F_w[kr-128,n]
__global__ void k_rowsum(const float* __restrict__ E_w, const float* __restrict__ F_w,
                         float* __restrict__ rowsums) {
  __shared__ float red[4];
  int row = blockIdx.x; // 0..255
  const float* src = (row < 128) ? (E_w + (long)row * NSEQ) : (F_w + (long)(row - 128) * NSEQ);
  float s = 0.f;
  for (int i = threadIdx.x; i < NSEQ; i += 256) s += src[i];
  for (int off = 32; off; off >>= 1) s += __shfl_xor(s, off);
  if ((threadIdx.x & 63) == 0) red[threadIdx.x >> 6] = s;
  __syncthreads();
  if (threadIdx.x == 0) rowsums[row] = red[0] + red[1] + red[2] + red[3];
}

// ---------------- window_reverse + transpose: x (2048,49,192) f32 -> xmT (32,192,3136) bf16 --------
// 256 threads, 64-n tile: float4 coalesced reads (768B runs), bf16x8 stores (128B runs per c-row)
__global__ void k_xT(const float* __restrict__ x, bf16* __restrict__ xmT) {
  __shared__ bf16 tile[64][196];  // stride 392B: 8B-aligned bf16x4 writes, modest read aliasing
  int blk = blockIdx.x;
  int b = blk / 49, n0 = (blk % 49) * 64;
  int tid = threadIdx.x;
  // read phase: 64 rows x 48 float4; consecutive 48 lanes share a source row
  for (int e = tid; e < 3072; e += 256) {
    int row = e / 48, c4 = e % 48;
    int n = n0 + row;
    int r = n / 56, cc = n % 56;
    long srcrow = (long)(b * 64 + (r / 7) * 8 + (cc / 7)) * 49 + (r % 7) * 7 + (cc % 7);
    float4 f = *(const float4*)(x + srcrow * 192 + c4 * 4);
    bf16x4 v; v[0]=(bf16)f.x; v[1]=(bf16)f.y; v[2]=(bf16)f.z; v[3]=(bf16)f.w;
    *(bf16x4*)&tile[row][c4 * 4] = v;
  }
  __syncthreads();
  // write phase: 192 c-rows x 8 chunks of 8 n; 8 consecutive threads -> 128B contiguous
  for (int e = tid; e < 1536; e += 256) {
    int c = e >> 3, k = e & 7;
    bf16x8 v;
    for (int jj = 0; jj < 8; jj++) v[jj] = tile[k * 8 + jj][c];
    *(bf16x8*)(xmT + ((long)b * 192 + c) * NSEQ + n0 + k * 8) = v;
  }
}

// ---------------- xlow GEMM split-K: partial[(b*12+t)*7+s] = [E;F]-tile @ xmT-tile^T over K-slice ---
__launch_bounds__(256)
__global__ void k_xlow(const bf16* __restrict__ EF, const bf16* __restrict__ xmT,
                       float* __restrict__ partial) {
  __shared__ bf16 As[64][72];
  __shared__ bf16 Bs[64][72];
  int idx = blockIdx.x;
  int s = idx % 7;
  int rem = (idx / 7) % 12;
  int b = idx / 84;
  int m0 = (rem / 3) * 64, n0 = (rem % 3) * 64;
  int kbase = s * 448;
  int tid = threadIdx.x;
  int wid = tid >> 6, lane = tid & 63;
  int wm = wid >> 1, wn = wid & 1;
  int lrow = lane & 15, lk = (lane >> 4) * 8;
  int srow = tid >> 2, skoff = (tid & 3) * 16;
  const bf16* Ap = EF + (long)(m0 + srow) * NSEQ + kbase + skoff;
  const bf16* Bp = xmT + ((long)b * 192 + n0 + srow) * NSEQ + kbase + skoff;
  f32x4 zero = {0.f, 0.f, 0.f, 0.f};
  f32x4 acc[2][2];
  for (int i = 0; i < 2; i++) for (int j = 0; j < 2; j++) acc[i][j] = zero;
  for (int k0 = 0; k0 < 448; k0 += 64) {
    *(bf16x8*)&As[srow][skoff]     = *(const bf16x8*)(Ap + k0);
    *(bf16x8*)&As[srow][skoff + 8] = *(const bf16x8*)(Ap + k0 + 8);
    *(bf16x8*)&Bs[srow][skoff]     = *(const bf16x8*)(Bp + k0);
    *(bf16x8*)&Bs[srow][skoff + 8] = *(const bf16x8*)(Bp + k0 + 8);
    __syncthreads();
    for (int ks = 0; ks < 2; ks++) {
      bf16x8 af[2], bfv[2];
      for (int i = 0; i < 2; i++) af[i]  = *(bf16x8*)&As[wm * 32 + 16 * i + lrow][ks * 32 + lk];
      for (int j = 0; j < 2; j++) bfv[j] = *(bf16x8*)&Bs[wn * 32 + 16 * j + lrow][ks * 32 + lk];
      for (int i = 0; i < 2; i++) for (int j = 0; j < 2; j++) acc[i][j] = MFMA16(af[i], bfv[j], acc[i][j]);
    }
    __syncthreads();
  }
  float* P = partial + (long)idx * 4096;
  for (int i = 0; i < 2; i++) for (int j = 0; j < 2; j++) for (int rr = 0; rr < 4; rr++) {
    int rl = wm * 32 + 16 * i + (lane >> 4) * 4 + rr;
    int cl = wn * 32 + 16 * j + lrow;
    P[rl * 64 + cl] = acc[i][j][rr];
  }
}

// ---------------- reduce 7 split-K partials -> el_fl (b,256,192) bf16 ------------------------------
__global__ void k_reduce(const float* __restrict__ partial, bf16* __restrict__ el_fl) {
  int idx = blockIdx.x;          // 32*12*4
  int qtr = idx & 3;
  int bt = idx >> 2;             // b*12 + t
  int t = bt % 12, b = bt / 12;
  const float* P = partial + (long)bt * 7 * 4096 + qtr * 1024;
  for (int i = 0; i < 4; i++) {
    int e = i * 256 + threadIdx.x;
    float sum = 0.f;
    for (int s = 0; s < 7; s++) sum += P[s * 4096 + e];
    int ee = qtr * 1024 + e;
    int lm = ee >> 6, lc = ee & 63;
    int kr = (t / 3) * 64 + lm, c = (t % 3) * 64 + lc;
    el_fl[((long)b * 256 + kr) * 192 + c] = (bf16)sum;
  }
}

// ---------------- low-rank proj: k_low = el@Wk^T + bias ; v_lowT = Wv@fl^T + bias (K=192 1-stage) --
__launch_bounds__(256)
__global__ void k_lowproj(const bf16* __restrict__ el_fl, const bf16* __restrict__ qkvw,
                          const float* __restrict__ qkv_b, const float* __restrict__ E_b,
                          const float* __restrict__ F_b, const float* __restrict__ rowsums,
                          bf16* __restrict__ k_low, bf16* __restrict__ v_lowT) {
  __shared__ bf16 As[64][200];
  __shared__ bf16 Bs[64][200];
  int idx = blockIdx.x;
  int b = idx / 12, rem = idx % 12;
  int type = rem / 6; rem %= 6;
  int bm, bn;
  if (type == 0) { bm = rem / 3; bn = rem % 3; }
  else           { bm = rem / 2; bn = rem % 2; }
  int m0 = bm * 64, n0 = bn * 64;
  int tid = threadIdx.x;
  int wid = tid >> 6, lane = tid & 63;
  int wm = wid >> 1, wn = wid & 1;
  int lrow = lane & 15, lk = (lane >> 4) * 8;
  int srow = tid >> 2, skoff = (tid & 3) * 16;
  const bf16* Ap; const bf16* Bp;
  if (type == 0) {
    Ap = el_fl + ((long)b * 256 + m0 + srow) * 192 + skoff;
    Bp = qkvw + (long)(192 + n0 + srow) * 192 + skoff;
  } else {
    Ap = qkvw + (long)(384 + m0 + srow) * 192 + skoff;
    Bp = el_fl + ((long)b * 256 + 128 + n0 + srow) * 192 + skoff;
  }
  for (int kk = 0; kk < 192; kk += 64) {
    *(bf16x8*)&As[srow][kk + skoff]     = *(const bf16x8*)(Ap + kk);
    *(bf16x8*)&As[srow][kk + skoff + 8] = *(const bf16x8*)(Ap + kk + 8);
    *(bf16x8*)&Bs[srow][kk + skoff]     = *(const bf16x8*)(Bp + kk);
    *(bf16x8*)&Bs[srow][kk + skoff + 8] = *(const bf16x8*)(Bp + kk + 8);
  }
  __syncthreads();
  f32x4 zero = {0.f, 0.f, 0.f, 0.f};
  f32x4 acc[2][2];
  for (int i = 0; i < 2; i++) for (int j = 0; j < 2; j++) acc[i][j] = zero;
  for (int ks = 0; ks < 6; ks++) {
    bf16x8 af[2], bfv[2];
    for (int i = 0; i < 2; i++) af[i]  = *(bf16x8*)&As[wm * 32 + 16 * i + lrow][ks * 32 + lk];
    for (int j = 0; j < 2; j++) bfv[j] = *(bf16x8*)&Bs[wn * 32 + 16 * j + lrow][ks * 32 + lk];
    for (int i = 0; i < 2; i++) for (int j = 0; j < 2; j++) acc[i][j] = MFMA16(af[i], bfv[j], acc[i][j]);
  }
  if (type == 0) {
    for (int i = 0; i < 2; i++) for (int j = 0; j < 2; j++) for (int rr = 0; rr < 4; rr++) {
      int kr = m0 + wm * 32 + 16 * i + (lane >> 4) * 4 + rr;
      int c = n0 + wn * 32 + 16 * j + lrow;
      float v = acc[i][j][rr] + rowsums[kr] * qkv_b[192 + c] + E_b[kr];
      k_low[((long)b * 128 + kr) * 192 + c] = (bf16)v;
    }
  } else {
    for (int i = 0; i < 2; i++) for (int j = 0; j < 2; j++) for (int rr = 0; rr < 4; rr++) {
      int c = m0 + wm * 32 + 16 * i + (lane >> 4) * 4 + rr;
      int kr = n0 + wn * 32 + 16 * j + lrow;
      float v = acc[i][j][rr] + rowsums[128 + kr] * qkv_b[384 + c] + F_b[kr];
      v_lowT[((long)b * 192 + c) * 128 + kr] = (bf16)v;
    }
  }
}

// ---------------- Q GEMM full-N: q(128 rows, all 192 cols) per block; Wq LDS-resident --------------
__launch_bounds__(256)
__global__ void k_qgemm2(const float* __restrict__ x, const bf16* __restrict__ qkvw,
                         const float* __restrict__ qkv_b, bf16* __restrict__ q) {
  __shared__ bf16 As[128][104];   // current K-chunk of A (128 x 96)
  __shared__ bf16 Bs[192][200];   // full Wq: row = out col c, 192 K entries
  long g0 = (long)blockIdx.x * 128;
  int tid = threadIdx.x;
  int wid = tid >> 6, lane = tid & 63;
  int lrow = lane & 15, lk = (lane >> 4) * 8;
  // stage full Wq
  {
    int koff = (tid & 3) * 48;
    for (int r0 = 0; r0 < 192; r0 += 64) {
      int row = r0 + (tid >> 2);
      const bf16* Bp = qkvw + (long)row * 192 + koff;
      for (int m = 0; m < 6; m++)
        *(bf16x8*)&Bs[row][koff + 8 * m] = *(const bf16x8*)(Bp + 8 * m);
    }
  }
  int arow = tid >> 1, half = tid & 1;
  long g = g0 + arow;
  int b = (int)(g / NSEQ), n = (int)(g % NSEQ);
  int r = n / 56, cc = n % 56;
  long srcrow = (long)(b * 64 + (r / 7) * 8 + (cc / 7)) * 49 + (r % 7) * 7 + (cc % 7);
  const float* Ap = x + srcrow * 192 + half * 48;
  f32x4 zero = {0.f, 0.f, 0.f, 0.f};
  f32x4 acc[2][12];
  for (int i = 0; i < 2; i++) for (int j = 0; j < 12; j++) acc[i][j] = zero;
  for (int k0 = 0; k0 < 192; k0 += 96) {
    for (int m = 0; m < 3; m++) {
      const float4* xp = (const float4*)(Ap + k0 + 16 * m);
      float4 f0 = xp[0], f1 = xp[1];
      float4 f2 = xp[2], f3 = xp[3];
      *(bf16x8*)&As[arow][half * 48 + 16 * m] = cvt8(f0, f1);
      *(bf16x8*)&As[arow][half * 48 + 16 * m + 8] = cvt8(f2, f3);
    }
    __syncthreads();
    for (int ks = 0; ks < 3; ks++) {
      bf16x8 af[2];
      for (int i = 0; i < 2; i++) af[i] = *(bf16x8*)&As[wid * 32 + 16 * i + lrow][ks * 32 + lk];
      for (int j = 0; j < 12; j++) {
        bf16x8 bv = *(bf16x8*)&Bs[16 * j + lrow][k0 + ks * 32 + lk];
        acc[0][j] = MFMA16(af[0], bv, acc[0][j]);
        acc[1][j] = MFMA16(af[1], bv, acc[1][j]);
      }
    }
    __syncthreads();
  }
  const float scale = 0.17677669529663687f; // 1/sqrt(32)
  for (int i = 0; i < 2; i++) for (int j = 0; j < 12; j++) for (int rr = 0; rr < 4; rr++) {
    long grow = g0 + wid * 32 + 16 * i + (lane >> 4) * 4 + rr;
    int c = 16 * j + lrow;
    float v = (acc[i][j][rr] + qkv_b[c]) * scale;
    q[grow * 192 + c] = (bf16)v;
  }
}

// ---------------- fused attention + projection -----------------------------------------------------
// block = (b, 64-row tile), all 6 heads. K/V/projw fragments read direct from global (L2-resident).
// P per-wave in LDS; O assembled in LDS (64x192); projection GEMM -> final f32 out.
__launch_bounds__(256)
__global__ void k_attnproj(const bf16* __restrict__ q, const bf16* __restrict__ k_low,
                           const bf16* __restrict__ v_lowT, const bf16* __restrict__ projw,
                           const float* __restrict__ proj_b, float* __restrict__ out) {
  __shared__ bf16 Ps[4][16][136];   // per-wave P staging (16 rows x 128 k)
  __shared__ bf16 Os[64][200];      // O assembly: 64 rows x 192 c
  int idx = blockIdx.x;
  int nt = idx % 49, b = idx / 49;
  int n0 = nt * 64;
  int tid = threadIdx.x;
  int wid = tid >> 6, lane = tid & 63;
  int lrow = lane & 15, hi = lane >> 4;
  int lk = hi * 8;
  int nrow = n0 + wid * 16 + lrow;
  // preload q fragments for all 6 heads (row = nrow, k = h*32+lk)
  bf16x8 qf[6];
  {
    const bf16* qp = q + ((long)b * NSEQ + nrow) * 192 + lk;
    for (int h = 0; h < 6; h++) qf[h] = *(const bf16x8*)(qp + h * 32);
  }
  f32x4 zero = {0.f, 0.f, 0.f, 0.f};
  const bf16* kbase = k_low + ((long)b * 128 + lrow) * 192 + lk;
  const bf16* vbase = v_lowT + ((long)b * 192 + lrow) * 128 + lk;
  for (int h = 0; h < 6; h++) {
    // S = q_h @ k_low_h^T : B-fragments direct from global (L2 hit)
    f32x4 s[8];
    const bf16* kp = kbase + h * 32;
    for (int f = 0; f < 8; f++)
      s[f] = MFMA16(qf[h], *(const bf16x8*)(kp + (long)f * 16 * 192), zero);
    // softmax over 128 k (8 in-reg blocks x 16 lanes)
    for (int rr = 0; rr < 4; rr++) {
      float m = s[0][rr];
      for (int f = 1; f < 8; f++) m = fmaxf(m, s[f][rr]);
      for (int off = 1; off < 16; off <<= 1) m = fmaxf(m, __shfl_xor(m, off));
      float sum = 0.f;
      for (int f = 0; f < 8; f++) { float p = __expf(s[f][rr] - m); s[f][rr] = p; sum += p; }
      for (int off = 1; off < 16; off <<= 1) sum += __shfl_xor(sum, off);
      float inv = 1.0f / sum;
      for (int f = 0; f < 8; f++) s[f][rr] *= inv;
    }
    __syncthreads();   // (A) prior head's Ps reads complete before overwrite
    for (int f = 0; f < 8; f++)
      for (int rr = 0; rr < 4; rr++)
        Ps[wid][hi * 4 + rr][16 * f + lrow] = (bf16)s[f][rr];
    __syncthreads();   // (B) Ps visible
    // O_h = P @ v_low_h : V B-fragments direct from global (L2 hit)
    f32x4 o[2]; o[0] = zero; o[1] = zero;
    const bf16* vp = vbase + (long)h * 32 * 128;
    for (int ks = 0; ks < 4; ks++) {
      bf16x8 pf = *(bf16x8*)&Ps[wid][lrow][ks * 32 + lk];
      for (int j = 0; j < 2; j++) {
        bf16x8 vf = *(const bf16x8*)(vp + (long)j * 16 * 128 + ks * 32);
        o[j] = MFMA16(pf, vf, o[j]);
      }
    }
    for (int j = 0; j < 2; j++)
      for (int rr = 0; rr < 4; rr++)
        Os[wid * 16 + hi * 4 + rr][h * 32 + 16 * j + lrow] = (bf16)o[j][rr];
  }
  __syncthreads();     // (C) O complete
  // projection: out(64x192) = Os @ projw^T + proj_b ; projw B-fragments from global (73.7KB, L2)
  f32x4 acc[12];
  for (int j = 0; j < 12; j++) acc[j] = zero;
  const bf16* wb = projw + (long)lrow * 192 + lk;
  for (int ks = 0; ks < 6; ks++) {
    bf16x8 af = *(bf16x8*)&Os[wid * 16 + lrow][ks * 32 + lk];
    for (int j = 0; j < 12; j++) {
      bf16x8 bv = *(const bf16x8*)(wb + (long)j * 16 * 192 + ks * 32);
      acc[j] = MFMA16(af, bv, acc[j]);
    }
  }
  for (int j = 0; j < 12; j++) {
    int co = 16 * j + lrow;
    float pb = proj_b[co];
    for (int rr = 0; rr < 4; rr++) {
      long grow = (long)b * NSEQ + n0 + wid * 16 + hi * 4 + rr;
      out[grow * 192 + co] = acc[j][rr] + pb;
    }
  }
}

extern "C" void kernel_launch(void* const* d_in, const int* in_sizes, int n_in,
                              void* d_out, int out_size, void* d_ws, size_t ws_size,
                              hipStream_t stream) {
  const float* x      = (const float*)d_in[0];
  const float* qkv_w  = (const float*)d_in[1];
  const float* qkv_b  = (const float*)d_in[2];
  const float* E_w    = (const float*)d_in[3];
  const float* E_b    = (const float*)d_in[4];
  const float* F_w    = (const float*)d_in[5];
  const float* F_b    = (const float*)d_in[6];
  const float* proj_w = (const float*)d_in[7];
  const float* proj_b = (const float*)d_in[8];
  float* out = (float*)d_out;

  char* ws = (char*)d_ws;
  size_t off = 0;
  auto alloc = [&](size_t bytes) { char* p = ws + off; off += (bytes + 255) & ~(size_t)255; return p; };
  bf16* qkvw     = (bf16*)alloc((size_t)110592 * 2);
  bf16* EF       = (bf16*)alloc((size_t)802816 * 2);
  bf16* projw    = (bf16*)alloc((size_t)36864 * 2);
  float* rowsums = (float*)alloc((size_t)256 * 4);
  bf16* xmT      = (bf16*)alloc((size_t)32 * 192 * NSEQ * 2);
  float* partial = (float*)alloc((size_t)2688 * 4096 * 4);      // 44 MB; aliased by q below
  bf16* q        = (bf16*)partial;                              // lifetimes disjoint (qgemm after reduce)
  bf16* el_fl    = (bf16*)alloc((size_t)32 * 256 * 192 * 2);
  bf16* k_low    = (bf16*)alloc((size_t)32 * 128 * 192 * 2);
  bf16* v_lowT   = (bf16*)alloc((size_t)32 * 192 * 128 * 2);

  k_convert<<<dim3(480), dim3(256), 0, stream>>>(qkv_w, E_w, F_w, proj_w, qkvw, EF, projw);
  k_rowsum<<<dim3(256), dim3(256), 0, stream>>>(E_w, F_w, rowsums);
  k_xT<<<dim3(32 * 49), dim3(256), 0, stream>>>(x, xmT);
  k_xlow<<<dim3(2688), dim3(256), 0, stream>>>(EF, xmT, partial);
  k_reduce<<<dim3(1536), dim3(256), 0, stream>>>(partial, el_fl);
  k_lowproj<<<dim3(384), dim3(256), 0, stream>>>(el_fl, qkvw, qkv_b, E_b, F_b, rowsums, k_low, v_lowT);
  k_qgemm2<<<dim3(784), dim3(256), 0, stream>>>(x, qkvw, qkv_b, q);
  k_attnproj<<<dim3(32 * 49), dim3(256), 0, stream>>>(q, k_low, v_lowT, projw, proj_b, out);
}

// Round 2
// 318.962 us; speedup vs baseline: 1.4700x; 1.4700x over previous
//
#include <hip/hip_runtime.h>

typedef __bf16 bf16;
typedef bf16 bf16x8 __attribute__((ext_vector_type(8)));
typedef bf16 bf16x4 __attribute__((ext_vector_type(4)));
typedef float f32x4 __attribute__((ext_vector_type(4)));

#define MFMA16(a,b,c) __builtin_amdgcn_mfma_f32_16x16x32_bf16(a,b,c,0,0,0)

#define NSEQ 3136
#define CDIM 192

__device__ inline bf16x8 cvt8(float4 a, float4 b) {
  bf16x8 r;
  r[0]=(bf16)a.x; r[1]=(bf16)a.y; r[2]=(bf16)a.z; r[3]=(bf16)a.w;
  r[4]=(bf16)b.x; r[5]=(bf16)b.y; r[6]=(bf16)b.z; r[7]=(bf16)b.w;
  return r;
}

__device__ inline bf16x4 cvt4(float4 a) {
  bf16x4 r;
  r[0]=(bf16)a.x; r[1]=(bf16)a.y; r[2]=(bf16)a.z; r[3]=(bf16)a.w;
  return r;
}

// ---------------- weight conversion fp32 -> bf16 (vectorized float4 -> bf16x4) ----------------
// region boundaries 110592 / 512000 / 913408 / 950272 are all multiples of 4.
__global__ void k_convert(const float* __restrict__ qkv_w, const float* __restrict__ E_w,
                          const float* __restrict__ F_w, const float* __restrict__ proj_w,
                          bf16* __restrict__ qkvw, bf16* __restrict__ EF, bf16* __restrict__ projw) {
  int i4 = blockIdx.x * blockDim.x + threadIdx.x;
  const int tot4 = 950272 / 4;
  for (; i4 < tot4; i4 += gridDim.x * blockDim.x) {
    int i = i4 * 4;
    float4 f;
    bf16* dst;
    if (i < 110592)      { f = *(const float4*)(qkv_w + i);            dst = qkvw + i; }
    else if (i < 512000) { f = *(const float4*)(E_w + (i - 110592));   dst = EF + (i - 110592); }
    else if (i < 913408) { f = *(const float4*)(F_w + (i - 512000));   dst = EF + (i - 110592); }
    else                 { f = *(const float4*)(proj_w + (i - 913408)); dst = projw + (i - 913408); }
    *(bf16x4*)dst = cvt4(f);
  }
}

// rowsums[kr] = sum_n E_w[kr,n] (kr<128) or F_w[kr-128,n]
__global__ void k_rowsum(const float* __restrict__ E_w, const float* __restrict__ F_w,
                         float* __restrict__ rowsums) {
  __shared__ float red[4];
  int row = blockIdx.x; // 0..255
  const float* src = (row < 128) ? (E_w + (long)row * NSEQ) : (F_w + (long)(row - 128) * NSEQ);
  float s = 0.f;
  for (int i = threadIdx.x; i < NSEQ; i += 256) s += src[i];
  for (int off = 32; off; off >>= 1) s += __shfl_xor(s, off);
  if ((threadIdx.x & 63) == 0) red[threadIdx.x >> 6] = s;
  __syncthreads();
  if (threadIdx.x == 0) rowsums[row] = red[0] + red[1] + red[2] + red[3];
}

// ---------------- window_reverse + transpose: x (2048,49,192) f32 -> xmT (32,192,3136) bf16 --------
// 256 threads, 64-n tile: float4 coalesced reads (768B runs), bf16x8 stores (128B runs per c-row)
__global__ void k_xT(const float* __restrict__ x, bf16* __restrict__ xmT) {
  __shared__ bf16 tile[64][196];  // stride 392B: 8B-aligned bf16x4 writes, modest read aliasing
  int blk = blockIdx.x;
  int b = blk / 49, n0 = (blk % 49) * 64;
  int tid = threadIdx.x;
  // read phase: 64 rows x 48 float4; consecutive 48 lanes share a source row
  for (int e = tid; e < 3072; e += 256) {
    int row = e / 48, c4 = e % 48;
    int n = n0 + row;
    int r = n / 56, cc = n % 56;
    long srcrow = (long)(b * 64 + (r / 7) * 8 + (cc / 7)) * 49 + (r % 7) * 7 + (cc % 7);
    float4 f = *(const float4*)(x + srcrow * 192 + c4 * 4);
    *(bf16x4*)&tile[row][c4 * 4] = cvt4(f);
  }
  __syncthreads();
  // write phase: 192 c-rows x 8 chunks of 8 n; 8 consecutive threads -> 128B contiguous
  for (int e = tid; e < 1536; e += 256) {
    int c = e >> 3, k = e & 7;
    bf16x8 v;
    for (int jj = 0; jj < 8; jj++) v[jj] = tile[k * 8 + jj][c];
    *(bf16x8*)(xmT + ((long)b * 192 + c) * NSEQ + n0 + k * 8) = v;
  }
}

// ---------------- xlow GEMM split-K: partial[(b*12+t)*7+s] = [E;F]-tile @ xmT-tile^T over K-slice ---
__launch_bounds__(256)
__global__ void k_xlow(const bf16* __restrict__ EF, const bf16* __restrict__ xmT,
                       float* __restrict__ partial) {
  __shared__ bf16 As[64][72];
  __shared__ bf16 Bs[64][72];
  int idx = blockIdx.x;
  int s = idx % 7;
  int rem = (idx / 7) % 12;
  int b = idx / 84;
  int m0 = (rem / 3) * 64, n0 = (rem % 3) * 64;
  int kbase = s * 448;
  int tid = threadIdx.x;
  int wid = tid >> 6, lane = tid & 63;
  int wm = wid >> 1, wn = wid & 1;
  int lrow = lane & 15, lk = (lane >> 4) * 8;
  int srow = tid >> 2, skoff = (tid & 3) * 16;
  const bf16* Ap = EF + (long)(m0 + srow) * NSEQ + kbase + skoff;
  const bf16* Bp = xmT + ((long)b * 192 + n0 + srow) * NSEQ + kbase + skoff;
  f32x4 zero = {0.f, 0.f, 0.f, 0.f};
  f32x4 acc[2][2];
  for (int i = 0; i < 2; i++) for (int j = 0; j < 2; j++) acc[i][j] = zero;
  for (int k0 = 0; k0 < 448; k0 += 64) {
    *(bf16x8*)&As[srow][skoff]     = *(const bf16x8*)(Ap + k0);
    *(bf16x8*)&As[srow][skoff + 8] = *(const bf16x8*)(Ap + k0 + 8);
    *(bf16x8*)&Bs[srow][skoff]     = *(const bf16x8*)(Bp + k0);
    *(bf16x8*)&Bs[srow][skoff + 8] = *(const bf16x8*)(Bp + k0 + 8);
    __syncthreads();
    for (int ks = 0; ks < 2; ks++) {
      bf16x8 af[2], bfv[2];
      for (int i = 0; i < 2; i++) af[i]  = *(bf16x8*)&As[wm * 32 + 16 * i + lrow][ks * 32 + lk];
      for (int j = 0; j < 2; j++) bfv[j] = *(bf16x8*)&Bs[wn * 32 + 16 * j + lrow][ks * 32 + lk];
      for (int i = 0; i < 2; i++) for (int j = 0; j < 2; j++) acc[i][j] = MFMA16(af[i], bfv[j], acc[i][j]);
    }
    __syncthreads();
  }
  float* P = partial + (long)idx * 4096;
  for (int i = 0; i < 2; i++) for (int j = 0; j < 2; j++) for (int rr = 0; rr < 4; rr++) {
    int rl = wm * 32 + 16 * i + (lane >> 4) * 4 + rr;
    int cl = wn * 32 + 16 * j + lrow;
    P[rl * 64 + cl] = acc[i][j][rr];
  }
}

// ---------------- reduce 7 split-K partials -> el_fl (b,256,192) bf16 (vectorized) -----------------
__global__ void k_reduce(const float* __restrict__ partial, bf16* __restrict__ el_fl) {
  int idx = blockIdx.x;          // 32*12*4
  int qtr = idx & 3;
  int bt = idx >> 2;             // b*12 + t
  int t = bt % 12, b = bt / 12;
  const float* P = partial + (long)bt * 7 * 4096 + qtr * 1024;
  int tid = threadIdx.x;
  float4 sum = {0.f, 0.f, 0.f, 0.f};
  for (int s = 0; s < 7; s++) {
    float4 f = *(const float4*)(P + s * 4096 + tid * 4);
    sum.x += f.x; sum.y += f.y; sum.z += f.z; sum.w += f.w;
  }
  int ee = qtr * 1024 + tid * 4;
  int lm = ee >> 6, lc = ee & 63;
  int kr = (t / 3) * 64 + lm, c = (t % 3) * 64 + lc;
  *(bf16x4*)(el_fl + ((long)b * 256 + kr) * 192 + c) = cvt4(sum);
}

// ---------------- low-rank proj: k_low = el@Wk^T + bias ; v_lowT = Wv@fl^T + bias (K=192 1-stage) --
__launch_bounds__(256)
__global__ void k_lowproj(const bf16* __restrict__ el_fl, const bf16* __restrict__ qkvw,
                          const float* __restrict__ qkv_b, const float* __restrict__ E_b,
                          const float* __restrict__ F_b, const float* __restrict__ rowsums,
                          bf16* __restrict__ k_low, bf16* __restrict__ v_lowT) {
  __shared__ bf16 As[64][200];
  __shared__ bf16 Bs[64][200];
  int idx = blockIdx.x;
  int b = idx / 12, rem = idx % 12;
  int type = rem / 6; rem %= 6;
  int bm, bn;
  if (type == 0) { bm = rem / 3; bn = rem % 3; }
  else           { bm = rem / 2; bn = rem % 2; }
  int m0 = bm * 64, n0 = bn * 64;
  int tid = threadIdx.x;
  int wid = tid >> 6, lane = tid & 63;
  int wm = wid >> 1, wn = wid & 1;
  int lrow = lane & 15, lk = (lane >> 4) * 8;
  int srow = tid >> 2, skoff = (tid & 3) * 16;
  const bf16* Ap; const bf16* Bp;
  if (type == 0) {
    Ap = el_fl + ((long)b * 256 + m0 + srow) * 192 + skoff;
    Bp = qkvw + (long)(192 + n0 + srow) * 192 + skoff;
  } else {
    Ap = qkvw + (long)(384 + m0 + srow) * 192 + skoff;
    Bp = el_fl + ((long)b * 256 + 128 + n0 + srow) * 192 + skoff;
  }
  for (int kk = 0; kk < 192; kk += 64) {
    *(bf16x8*)&As[srow][kk + skoff]     = *(const bf16x8*)(Ap + kk);
    *(bf16x8*)&As[srow][kk + skoff + 8] = *(const bf16x8*)(Ap + kk + 8);
    *(bf16x8*)&Bs[srow][kk + skoff]     = *(const bf16x8*)(Bp + kk);
    *(bf16x8*)&Bs[srow][kk + skoff + 8] = *(const bf16x8*)(Bp + kk + 8);
  }
  __syncthreads();
  f32x4 zero = {0.f, 0.f, 0.f, 0.f};
  f32x4 acc[2][2];
  for (int i = 0; i < 2; i++) for (int j = 0; j < 2; j++) acc[i][j] = zero;
  for (int ks = 0; ks < 6; ks++) {
    bf16x8 af[2], bfv[2];
    for (int i = 0; i < 2; i++) af[i]  = *(bf16x8*)&As[wm * 32 + 16 * i + lrow][ks * 32 + lk];
    for (int j = 0; j < 2; j++) bfv[j] = *(bf16x8*)&Bs[wn * 32 + 16 * j + lrow][ks * 32 + lk];
    for (int i = 0; i < 2; i++) for (int j = 0; j < 2; j++) acc[i][j] = MFMA16(af[i], bfv[j], acc[i][j]);
  }
  if (type == 0) {
    for (int i = 0; i < 2; i++) for (int j = 0; j < 2; j++) for (int rr = 0; rr < 4; rr++) {
      int kr = m0 + wm * 32 + 16 * i + (lane >> 4) * 4 + rr;
      int c = n0 + wn * 32 + 16 * j + lrow;
      float v = acc[i][j][rr] + rowsums[kr] * qkv_b[192 + c] + E_b[kr];
      k_low[((long)b * 128 + kr) * 192 + c] = (bf16)v;
    }
  } else {
    for (int i = 0; i < 2; i++) for (int j = 0; j < 2; j++) for (int rr = 0; rr < 4; rr++) {
      int c = m0 + wm * 32 + 16 * i + (lane >> 4) * 4 + rr;
      int kr = n0 + wn * 32 + 16 * j + lrow;
      float v = acc[i][j][rr] + rowsums[128 + kr] * qkv_b[384 + c] + F_b[kr];
      v_lowT[((long)b * 192 + c) * 128 + kr] = (bf16)v;
    }
  }
}

// ---------------- Q GEMM full-N: q(128 rows, all 192 cols) per block; Wq LDS-resident --------------
__launch_bounds__(256)
__global__ void k_qgemm2(const float* __restrict__ x, const bf16* __restrict__ qkvw,
                         const float* __restrict__ qkv_b, bf16* __restrict__ q) {
  __shared__ bf16 As[128][104];   // current K-chunk of A (128 x 96)
  __shared__ bf16 Bs[192][200];   // full Wq: row = out col c, 192 K entries
  long g0 = (long)blockIdx.x * 128;
  int tid = threadIdx.x;
  int wid = tid >> 6, lane = tid & 63;
  int lrow = lane & 15, lk = (lane >> 4) * 8;
  // stage full Wq
  {
    int koff = (tid & 3) * 48;
    for (int r0 = 0; r0 < 192; r0 += 64) {
      int row = r0 + (tid >> 2);
      const bf16* Bp = qkvw + (long)row * 192 + koff;
      for (int m = 0; m < 6; m++)
        *(bf16x8*)&Bs[row][koff + 8 * m] = *(const bf16x8*)(Bp + 8 * m);
    }
  }
  int arow = tid >> 1, half = tid & 1;
  long g = g0 + arow;
  int b = (int)(g / NSEQ), n = (int)(g % NSEQ);
  int r = n / 56, cc = n % 56;
  long srcrow = (long)(b * 64 + (r / 7) * 8 + (cc / 7)) * 49 + (r % 7) * 7 + (cc % 7);
  const float* Ap = x + srcrow * 192 + half * 48;
  f32x4 zero = {0.f, 0.f, 0.f, 0.f};
  f32x4 acc[2][12];
  for (int i = 0; i < 2; i++) for (int j = 0; j < 12; j++) acc[i][j] = zero;
  for (int k0 = 0; k0 < 192; k0 += 96) {
    for (int m = 0; m < 3; m++) {
      const float4* xp = (const float4*)(Ap + k0 + 16 * m);
      float4 f0 = xp[0], f1 = xp[1];
      float4 f2 = xp[2], f3 = xp[3];
      *(bf16x8*)&As[arow][half * 48 + 16 * m] = cvt8(f0, f1);
      *(bf16x8*)&As[arow][half * 48 + 16 * m + 8] = cvt8(f2, f3);
    }
    __syncthreads();
    for (int ks = 0; ks < 3; ks++) {
      bf16x8 af[2];
      for (int i = 0; i < 2; i++) af[i] = *(bf16x8*)&As[wid * 32 + 16 * i + lrow][ks * 32 + lk];
      for (int j = 0; j < 12; j++) {
        bf16x8 bv = *(bf16x8*)&Bs[16 * j + lrow][k0 + ks * 32 + lk];
        acc[0][j] = MFMA16(af[0], bv, acc[0][j]);
        acc[1][j] = MFMA16(af[1], bv, acc[1][j]);
      }
    }
    __syncthreads();
  }
  const float scale = 0.17677669529663687f; // 1/sqrt(32)
  for (int i = 0; i < 2; i++) for (int j = 0; j < 12; j++) for (int rr = 0; rr < 4; rr++) {
    long grow = g0 + wid * 32 + 16 * i + (lane >> 4) * 4 + rr;
    int c = 16 * j + lrow;
    float v = (acc[i][j][rr] + qkv_b[c]) * scale;
    q[grow * 192 + c] = (bf16)v;
  }
}

// ---------------- fused attention: per (b,h,64-row tile): S = q@k_low^T, softmax, O = P@v_low -----
__launch_bounds__(256)
__global__ void k_attn(const bf16* __restrict__ q, const bf16* __restrict__ k_low,
                       const bf16* __restrict__ v_lowT, bf16* __restrict__ out_att) {
  __shared__ bf16 Ks[128][40];
  __shared__ bf16 Vs[32][136];
  __shared__ bf16 Ps[4][16][136];
  int idx = blockIdx.x;
  int nt = idx % 49, bh = idx / 49;
  int h = bh % 6, b = bh / 6;
  int n0 = nt * 64;
  int tid = threadIdx.x;
  int wid = tid >> 6, lane = tid & 63;
  int lrow = lane & 15, lk = (lane >> 4) * 8;
  {
    int row = tid >> 1, koff = (tid & 1) * 16;
    const bf16* src = k_low + ((long)b * 128 + row) * 192 + h * 32 + koff;
    *(bf16x8*)&Ks[row][koff] = *(const bf16x8*)src;
    *(bf16x8*)&Ks[row][koff + 8] = *(const bf16x8*)(src + 8);
  }
  {
    int row = tid >> 3, koff = (tid & 7) * 16;
    const bf16* src = v_lowT + ((long)b * 192 + h * 32 + row) * 128 + koff;
    *(bf16x8*)&Vs[row][koff] = *(const bf16x8*)src;
    *(bf16x8*)&Vs[row][koff + 8] = *(const bf16x8*)(src + 8);
  }
  int nrow = n0 + wid * 16 + lrow;
  bf16x8 qf = *(const bf16x8*)(q + ((long)b * NSEQ + nrow) * 192 + h * 32 + lk);
  __syncthreads();
  f32x4 zero = {0.f, 0.f, 0.f, 0.f};
  f32x4 s[8];
  for (int f = 0; f < 8; f++) {
    bf16x8 kf = *(bf16x8*)&Ks[16 * f + lrow][lk];
    s[f] = MFMA16(qf, kf, zero);
  }
  for (int rr = 0; rr < 4; rr++) {
    float m = s[0][rr];
    for (int f = 1; f < 8; f++) m = fmaxf(m, s[f][rr]);
    for (int off = 1; off < 16; off <<= 1) m = fmaxf(m, __shfl_xor(m, off));
    float sum = 0.f;
    for (int f = 0; f < 8; f++) { float p = __expf(s[f][rr] - m); s[f][rr] = p; sum += p; }
    for (int off = 1; off < 16; off <<= 1) sum += __shfl_xor(sum, off);
    float inv = 1.0f / sum;
    for (int f = 0; f < 8; f++) s[f][rr] *= inv;
  }
  for (int f = 0; f < 8; f++)
    for (int rr = 0; rr < 4; rr++)
      Ps[wid][(lane >> 4) * 4 + rr][16 * f + lrow] = (bf16)s[f][rr];
  __syncthreads();
  f32x4 o[2];
  o[0] = zero; o[1] = zero;
  for (int ks = 0; ks < 4; ks++) {
    bf16x8 pf = *(bf16x8*)&Ps[wid][lrow][ks * 32 + lk];
    for (int j = 0; j < 2; j++) {
      bf16x8 vf = *(bf16x8*)&Vs[16 * j + lrow][ks * 32 + lk];
      o[j] = MFMA16(pf, vf, o[j]);
    }
  }
  for (int j = 0; j < 2; j++) for (int rr = 0; rr < 4; rr++) {
    int nn = n0 + wid * 16 + (lane >> 4) * 4 + rr;
    out_att[((long)b * NSEQ + nn) * 192 + h * 32 + 16 * j + lrow] = (bf16)o[j][rr];
  }
}

// ---------------- proj GEMM full-N: out(128 rows, all 192 cols) fp32; projw LDS-resident -----------
__launch_bounds__(256)
__global__ void k_proj(const bf16* __restrict__ oa, const bf16* __restrict__ projw,
                       const float* __restrict__ proj_b, float* __restrict__ out) {
  __shared__ bf16 As[128][104];
  __shared__ bf16 Bs[192][200];
  long g0 = (long)blockIdx.x * 128;
  int tid = threadIdx.x;
  int wid = tid >> 6, lane = tid & 63;
  int lrow = lane & 15, lk = (lane >> 4) * 8;
  {
    int koff = (tid & 3) * 48;
    for (int r0 = 0; r0 < 192; r0 += 64) {
      int row = r0 + (tid >> 2);
      const bf16* Bp = projw + (long)row * 192 + koff;
      for (int m = 0; m < 6; m++)
        *(bf16x8*)&Bs[row][koff + 8 * m] = *(const bf16x8*)(Bp + 8 * m);
    }
  }
  int arow = tid >> 1, half = tid & 1;
  const bf16* Ap = oa + (g0 + arow) * 192 + half * 48;
  f32x4 zero = {0.f, 0.f, 0.f, 0.f};
  f32x4 acc[2][12];
  for (int i = 0; i < 2; i++) for (int j = 0; j < 12; j++) acc[i][j] = zero;
  for (int k0 = 0; k0 < 192; k0 += 96) {
    for (int m = 0; m < 6; m++)
      *(bf16x8*)&As[arow][half * 48 + 8 * m] = *(const bf16x8*)(Ap + k0 + 8 * m);
    __syncthreads();
    for (int ks = 0; ks < 3; ks++) {
      bf16x8 af[2];
      for (int i = 0; i < 2; i++) af[i] = *(bf16x8*)&As[wid * 32 + 16 * i + lrow][ks * 32 + lk];
      for (int j = 0; j < 12; j++) {
        bf16x8 bv = *(bf16x8*)&Bs[16 * j + lrow][k0 + ks * 32 + lk];
        acc[0][j] = MFMA16(af[0], bv, acc[0][j]);
        acc[1][j] = MFMA16(af[1], bv, acc[1][j]);
      }
    }
    __syncthreads();
  }
  for (int i = 0; i < 2; i++) for (int j = 0; j < 12; j++) for (int rr = 0; rr < 4; rr++) {
    long grow = g0 + wid * 32 + 16 * i + (lane >> 4) * 4 + rr;
    int c = 16 * j + lrow;
    out[grow * 192 + c] = acc[i][j][rr] + proj_b[c];
  }
}

extern "C" void kernel_launch(void* const* d_in, const int* in_sizes, int n_in,
                              void* d_out, int out_size, void* d_ws, size_t ws_size,
                              hipStream_t stream) {
  const float* x      = (const float*)d_in[0];
  const float* qkv_w  = (const float*)d_in[1];
  const float* qkv_b  = (const float*)d_in[2];
  const float* E_w    = (const float*)d_in[3];
  const float* E_b    = (const float*)d_in[4];
  const float* F_w    = (const float*)d_in[5];
  const float* F_b    = (const float*)d_in[6];
  const float* proj_w = (const float*)d_in[7];
  const float* proj_b = (const float*)d_in[8];
  float* out = (float*)d_out;

  char* ws = (char*)d_ws;
  size_t off = 0;
  auto alloc = [&](size_t bytes) { char* p = ws + off; off += (bytes + 255) & ~(size_t)255; return p; };
  bf16* qkvw     = (bf16*)alloc((size_t)110592 * 2);
  bf16* EF       = (bf16*)alloc((size_t)802816 * 2);
  bf16* projw    = (bf16*)alloc((size_t)36864 * 2);
  float* rowsums = (float*)alloc((size_t)256 * 4);
  bf16* xmT      = (bf16*)alloc((size_t)32 * 192 * NSEQ * 2);   // reused as out_att after xlow
  float* partial = (float*)alloc((size_t)2688 * 4096 * 4);      // 44 MB; aliased by q below
  bf16* q        = (bf16*)partial;                              // lifetimes disjoint (qgemm after reduce)
  bf16* el_fl    = (bf16*)alloc((size_t)32 * 256 * 192 * 2);
  bf16* k_low    = (bf16*)alloc((size_t)32 * 128 * 192 * 2);
  bf16* v_lowT   = (bf16*)alloc((size_t)32 * 192 * 128 * 2);
  bf16* out_att  = xmT;

  k_convert<<<dim3(480), dim3(256), 0, stream>>>(qkv_w, E_w, F_w, proj_w, qkvw, EF, projw);
  k_rowsum<<<dim3(256), dim3(256), 0, stream>>>(E_w, F_w, rowsums);
  k_xT<<<dim3(32 * 49), dim3(256), 0, stream>>>(x, xmT);
  k_xlow<<<dim3(2688), dim3(256), 0, stream>>>(EF, xmT, partial);
  k_reduce<<<dim3(1536), dim3(256), 0, stream>>>(partial, el_fl);
  k_lowproj<<<dim3(384), dim3(256), 0, stream>>>(el_fl, qkvw, qkv_b, E_b, F_b, rowsums, k_low, v_lowT);
  k_qgemm2<<<dim3(784), dim3(256), 0, stream>>>(x, qkvw, qkv_b, q);
  k_attn<<<dim3(32 * 6 * 49), dim3(256), 0, stream>>>(q, k_low, v_lowT, out_att);
  k_proj<<<dim3(784), dim3(256), 0, stream>>>(out_att, projw, proj_b, out);
}

// Round 3
// 300.468 us; speedup vs baseline: 1.5604x; 1.0615x over previous
//
#include <hip/hip_runtime.h>

typedef __bf16 bf16;
typedef bf16 bf16x8 __attribute__((ext_vector_type(8)));
typedef bf16 bf16x4 __attribute__((ext_vector_type(4)));
typedef float f32x4 __attribute__((ext_vector_type(4)));

#define MFMA16(a,b,c) __builtin_amdgcn_mfma_f32_16x16x32_bf16(a,b,c,0,0,0)

#define NSEQ 3136
#define CDIM 192

__device__ inline bf16x8 cvt8(float4 a, float4 b) {
  bf16x8 r;
  r[0]=(bf16)a.x; r[1]=(bf16)a.y; r[2]=(bf16)a.z; r[3]=(bf16)a.w;
  r[4]=(bf16)b.x; r[5]=(bf16)b.y; r[6]=(bf16)b.z; r[7]=(bf16)b.w;
  return r;
}

__device__ inline bf16x4 cvt4(float4 a) {
  bf16x4 r;
  r[0]=(bf16)a.x; r[1]=(bf16)a.y; r[2]=(bf16)a.z; r[3]=(bf16)a.w;
  return r;
}

// ---------------- weight conversion fp32 -> bf16 (vectorized float4 -> bf16x4) ----------------
__global__ void k_convert(const float* __restrict__ qkv_w, const float* __restrict__ E_w,
                          const float* __restrict__ F_w, const float* __restrict__ proj_w,
                          bf16* __restrict__ qkvw, bf16* __restrict__ EF, bf16* __restrict__ projw) {
  int i4 = blockIdx.x * blockDim.x + threadIdx.x;
  const int tot4 = 950272 / 4;
  for (; i4 < tot4; i4 += gridDim.x * blockDim.x) {
    int i = i4 * 4;
    float4 f;
    bf16* dst;
    if (i < 110592)      { f = *(const float4*)(qkv_w + i);            dst = qkvw + i; }
    else if (i < 512000) { f = *(const float4*)(E_w + (i - 110592));   dst = EF + (i - 110592); }
    else if (i < 913408) { f = *(const float4*)(F_w + (i - 512000));   dst = EF + (i - 110592); }
    else                 { f = *(const float4*)(proj_w + (i - 913408)); dst = projw + (i - 913408); }
    *(bf16x4*)dst = cvt4(f);
  }
}

// rowsums[kr] = sum_n E_w[kr,n] (kr<128) or F_w[kr-128,n]  (float4 vectorized: 3136 = 784*4)
__global__ void k_rowsum(const float* __restrict__ E_w, const float* __restrict__ F_w,
                         float* __restrict__ rowsums) {
  __shared__ float red[4];
  int row = blockIdx.x; // 0..255
  const float* src = (row < 128) ? (E_w + (long)row * NSEQ) : (F_w + (long)(row - 128) * NSEQ);
  float s = 0.f;
  for (int i = threadIdx.x; i < 784; i += 256) {
    float4 f = *(const float4*)(src + i * 4);
    s += f.x + f.y + f.z + f.w;
  }
  for (int off = 32; off; off >>= 1) s += __shfl_xor(s, off);
  if ((threadIdx.x & 63) == 0) red[threadIdx.x >> 6] = s;
  __syncthreads();
  if (threadIdx.x == 0) rowsums[row] = red[0] + red[1] + red[2] + red[3];
}

// ---------------- window_reverse + transpose: x (2048,49,192) f32 -> xmT (32,192,3136) bf16 --------
__global__ void k_xT(const float* __restrict__ x, bf16* __restrict__ xmT) {
  __shared__ bf16 tile[64][196];
  int blk = blockIdx.x;
  int b = blk / 49, n0 = (blk % 49) * 64;
  int tid = threadIdx.x;
  for (int e = tid; e < 3072; e += 256) {
    int row = e / 48, c4 = e % 48;
    int n = n0 + row;
    int r = n / 56, cc = n % 56;
    long srcrow = (long)(b * 64 + (r / 7) * 8 + (cc / 7)) * 49 + (r % 7) * 7 + (cc % 7);
    float4 f = *(const float4*)(x + srcrow * 192 + c4 * 4);
    *(bf16x4*)&tile[row][c4 * 4] = cvt4(f);
  }
  __syncthreads();
  for (int e = tid; e < 1536; e += 256) {
    int c = e >> 3, k = e & 7;
    bf16x8 v;
    for (int jj = 0; jj < 8; jj++) v[jj] = tile[k * 8 + jj][c];
    *(bf16x8*)(xmT + ((long)b * 192 + c) * NSEQ + n0 + k * 8) = v;
  }
}

// ---------------- xlow GEMM: one block per (b, K-slice); full 256x192 tile, K=448 ------------------
// 8 waves (512 thr), wave tile 128x48 (8 M-frags x 3 N-frags). xmT read exactly once.
__launch_bounds__(512)
__global__ void k_xlow(const bf16* __restrict__ EF, const bf16* __restrict__ xmT,
                       float* __restrict__ partial) {
  __shared__ bf16 As[256][72];   // EF rows 0..255, current 64-k chunk
  __shared__ bf16 Bs[192][72];   // xmT channel rows 0..191, current 64-k chunk
  int idx = blockIdx.x;          // b*7 + s
  int s = idx % 7, b = idx / 7;
  int kbase = s * 448;
  int tid = threadIdx.x;
  int wid = tid >> 6, lane = tid & 63;
  int wm = wid >> 2, wn = wid & 3;        // 2 x 4 wave grid
  int lrow = lane & 15, hi = lane >> 4, lk = hi * 8;
  f32x4 zero = {0.f, 0.f, 0.f, 0.f};
  f32x4 acc[8][3];
  for (int i = 0; i < 8; i++) for (int j = 0; j < 3; j++) acc[i][j] = zero;
  for (int k0 = 0; k0 < 448; k0 += 64) {
    for (int i = 0; i < 4; i++) {          // A: 256 rows x 8 chunks of 8k
      int unit = i * 512 + tid;
      int row = unit >> 3, koff = (unit & 7) * 8;
      *(bf16x8*)&As[row][koff] = *(const bf16x8*)(EF + (long)row * NSEQ + kbase + k0 + koff);
    }
    for (int i = 0; i < 3; i++) {          // B: 192 rows x 8 chunks of 8k
      int unit = i * 512 + tid;
      int row = unit >> 3, koff = (unit & 7) * 8;
      *(bf16x8*)&Bs[row][koff] = *(const bf16x8*)(xmT + ((long)b * 192 + row) * NSEQ + kbase + k0 + koff);
    }
    __syncthreads();
    for (int ks = 0; ks < 2; ks++) {
      bf16x8 af[8], bfv[3];
      for (int i = 0; i < 8; i++) af[i]  = *(bf16x8*)&As[wm * 128 + 16 * i + lrow][ks * 32 + lk];
      for (int j = 0; j < 3; j++) bfv[j] = *(bf16x8*)&Bs[wn * 48 + 16 * j + lrow][ks * 32 + lk];
      for (int i = 0; i < 8; i++) for (int j = 0; j < 3; j++) acc[i][j] = MFMA16(af[i], bfv[j], acc[i][j]);
    }
    __syncthreads();
  }
  float* P = partial + (long)idx * 49152;  // 256 x 192 f32
  for (int i = 0; i < 8; i++) for (int j = 0; j < 3; j++) for (int rr = 0; rr < 4; rr++) {
    int rl = wm * 128 + 16 * i + hi * 4 + rr;
    int cl = wn * 48 + 16 * j + lrow;
    P[rl * 192 + cl] = acc[i][j][rr];
  }
}

// ---------------- reduce 7 split-K partials -> el_fl (b,256,192) bf16 (linear, vectorized) ---------
__global__ void k_reduce(const float* __restrict__ partial, bf16* __restrict__ el_fl) {
  int blk = blockIdx.x;          // 32 b x 48 chunks
  int b = blk / 48, ch = blk % 48;
  long e = (long)ch * 1024 + threadIdx.x * 4;   // 0..49151
  const float* P = partial + (long)b * 7 * 49152 + e;
  float4 sum = {0.f, 0.f, 0.f, 0.f};
  for (int s = 0; s < 7; s++) {
    float4 f = *(const float4*)(P + (long)s * 49152);
    sum.x += f.x; sum.y += f.y; sum.z += f.z; sum.w += f.w;
  }
  *(bf16x4*)(el_fl + (long)b * 49152 + e) = cvt4(sum);
}

// ---------------- low-rank proj: k_low = el@Wk^T + bias ; v_lowT = Wv@fl^T + bias (K=192 1-stage) --
__launch_bounds__(256)
__global__ void k_lowproj(const bf16* __restrict__ el_fl, const bf16* __restrict__ qkvw,
                          const float* __restrict__ qkv_b, const float* __restrict__ E_b,
                          const float* __restrict__ F_b, const float* __restrict__ rowsums,
                          bf16* __restrict__ k_low, bf16* __restrict__ v_lowT) {
  __shared__ bf16 As[64][200];
  __shared__ bf16 Bs[64][200];
  int idx = blockIdx.x;
  int b = idx / 12, rem = idx % 12;
  int type = rem / 6; rem %= 6;
  int bm, bn;
  if (type == 0) { bm = rem / 3; bn = rem % 3; }
  else           { bm = rem / 2; bn = rem % 2; }
  int m0 = bm * 64, n0 = bn * 64;
  int tid = threadIdx.x;
  int wid = tid >> 6, lane = tid & 63;
  int wm = wid >> 1, wn = wid & 1;
  int lrow = lane & 15, lk = (lane >> 4) * 8;
  int srow = tid >> 2, skoff = (tid & 3) * 16;
  const bf16* Ap; const bf16* Bp;
  if (type == 0) {
    Ap = el_fl + ((long)b * 256 + m0 + srow) * 192 + skoff;
    Bp = qkvw + (long)(192 + n0 + srow) * 192 + skoff;
  } else {
    Ap = qkvw + (long)(384 + m0 + srow) * 192 + skoff;
    Bp = el_fl + ((long)b * 256 + 128 + n0 + srow) * 192 + skoff;
  }
  for (int kk = 0; kk < 192; kk += 64) {
    *(bf16x8*)&As[srow][kk + skoff]     = *(const bf16x8*)(Ap + kk);
    *(bf16x8*)&As[srow][kk + skoff + 8] = *(const bf16x8*)(Ap + kk + 8);
    *(bf16x8*)&Bs[srow][kk + skoff]     = *(const bf16x8*)(Bp + kk);
    *(bf16x8*)&Bs[srow][kk + skoff + 8] = *(const bf16x8*)(Bp + kk + 8);
  }
  __syncthreads();
  f32x4 zero = {0.f, 0.f, 0.f, 0.f};
  f32x4 acc[2][2];
  for (int i = 0; i < 2; i++) for (int j = 0; j < 2; j++) acc[i][j] = zero;
  for (int ks = 0; ks < 6; ks++) {
    bf16x8 af[2], bfv[2];
    for (int i = 0; i < 2; i++) af[i]  = *(bf16x8*)&As[wm * 32 + 16 * i + lrow][ks * 32 + lk];
    for (int j = 0; j < 2; j++) bfv[j] = *(bf16x8*)&Bs[wn * 32 + 16 * j + lrow][ks * 32 + lk];
    for (int i = 0; i < 2; i++) for (int j = 0; j < 2; j++) acc[i][j] = MFMA16(af[i], bfv[j], acc[i][j]);
  }
  if (type == 0) {
    for (int i = 0; i < 2; i++) for (int j = 0; j < 2; j++) for (int rr = 0; rr < 4; rr++) {
      int kr = m0 + wm * 32 + 16 * i + (lane >> 4) * 4 + rr;
      int c = n0 + wn * 32 + 16 * j + lrow;
      float v = acc[i][j][rr] + rowsums[kr] * qkv_b[192 + c] + E_b[kr];
      k_low[((long)b * 128 + kr) * 192 + c] = (bf16)v;
    }
  } else {
    for (int i = 0; i < 2; i++) for (int j = 0; j < 2; j++) for (int rr = 0; rr < 4; rr++) {
      int c = m0 + wm * 32 + 16 * i + (lane >> 4) * 4 + rr;
      int kr = n0 + wn * 32 + 16 * j + lrow;
      float v = acc[i][j][rr] + rowsums[128 + kr] * qkv_b[384 + c] + F_b[kr];
      v_lowT[((long)b * 192 + c) * 128 + kr] = (bf16)v;
    }
  }
}

// ---------------- Q GEMM full-N: q(128 rows, all 192 cols) per block; Wq LDS-resident --------------
__launch_bounds__(256)
__global__ void k_qgemm2(const float* __restrict__ x, const bf16* __restrict__ qkvw,
                         const float* __restrict__ qkv_b, bf16* __restrict__ q) {
  __shared__ bf16 As[128][104];
  __shared__ bf16 Bs[192][200];
  long g0 = (long)blockIdx.x * 128;
  int tid = threadIdx.x;
  int wid = tid >> 6, lane = tid & 63;
  int lrow = lane & 15, lk = (lane >> 4) * 8;
  {
    int koff = (tid & 3) * 48;
    for (int r0 = 0; r0 < 192; r0 += 64) {
      int row = r0 + (tid >> 2);
      const bf16* Bp = qkvw + (long)row * 192 + koff;
      for (int m = 0; m < 6; m++)
        *(bf16x8*)&Bs[row][koff + 8 * m] = *(const bf16x8*)(Bp + 8 * m);
    }
  }
  int arow = tid >> 1, half = tid & 1;
  long g = g0 + arow;
  int b = (int)(g / NSEQ), n = (int)(g % NSEQ);
  int r = n / 56, cc = n % 56;
  long srcrow = (long)(b * 64 + (r / 7) * 8 + (cc / 7)) * 49 + (r % 7) * 7 + (cc % 7);
  const float* Ap = x + srcrow * 192 + half * 48;
  f32x4 zero = {0.f, 0.f, 0.f, 0.f};
  f32x4 acc[2][12];
  for (int i = 0; i < 2; i++) for (int j = 0; j < 12; j++) acc[i][j] = zero;
  for (int k0 = 0; k0 < 192; k0 += 96) {
    for (int m = 0; m < 3; m++) {
      const float4* xp = (const float4*)(Ap + k0 + 16 * m);
      float4 f0 = xp[0], f1 = xp[1];
      float4 f2 = xp[2], f3 = xp[3];
      *(bf16x8*)&As[arow][half * 48 + 16 * m] = cvt8(f0, f1);
      *(bf16x8*)&As[arow][half * 48 + 16 * m + 8] = cvt8(f2, f3);
    }
    __syncthreads();
    for (int ks = 0; ks < 3; ks++) {
      bf16x8 af[2];
      for (int i = 0; i < 2; i++) af[i] = *(bf16x8*)&As[wid * 32 + 16 * i + lrow][ks * 32 + lk];
      for (int j = 0; j < 12; j++) {
        bf16x8 bv = *(bf16x8*)&Bs[16 * j + lrow][k0 + ks * 32 + lk];
        acc[0][j] = MFMA16(af[0], bv, acc[0][j]);
        acc[1][j] = MFMA16(af[1], bv, acc[1][j]);
      }
    }
    __syncthreads();
  }
  const float scale = 0.17677669529663687f; // 1/sqrt(32)
  for (int i = 0; i < 2; i++) for (int j = 0; j < 12; j++) for (int rr = 0; rr < 4; rr++) {
    long grow = g0 + wid * 32 + 16 * i + (lane >> 4) * 4 + rr;
    int c = 16 * j + lrow;
    float v = (acc[i][j][rr] + qkv_b[c]) * scale;
    q[grow * 192 + c] = (bf16)v;
  }
}

// ---------------- fused attention: swapped QK^T -> in-register softmax (T12-lite) ------------------
// S^T = K @ Q^T: lane holds its q-row's 32 S values (q fixed = lrow); reduce = 31 in-reg + 2 shfl.
// P stored to LDS as bf16x4 packs; PV read side unchanged ([q][k] layout).
__launch_bounds__(256)
__global__ void k_attn(const bf16* __restrict__ q, const bf16* __restrict__ k_low,
                       const bf16* __restrict__ v_lowT, bf16* __restrict__ out_att) {
  __shared__ bf16 Ks[128][40];
  __shared__ bf16 Vs[32][136];
  __shared__ bf16 Ps[4][16][136];
  int idx = blockIdx.x;
  int nt = idx % 49, bh = idx / 49;
  int h = bh % 6, b = bh / 6;
  int n0 = nt * 64;
  int tid = threadIdx.x;
  int wid = tid >> 6, lane = tid & 63;
  int lrow = lane & 15, hi = lane >> 4, lk = hi * 8;
  {
    int row = tid >> 1, koff = (tid & 1) * 16;
    const bf16* src = k_low + ((long)b * 128 + row) * 192 + h * 32 + koff;
    *(bf16x8*)&Ks[row][koff] = *(const bf16x8*)src;
    *(bf16x8*)&Ks[row][koff + 8] = *(const bf16x8*)(src + 8);
  }
  {
    int row = tid >> 3, koff = (tid & 7) * 16;
    const bf16* src = v_lowT + ((long)b * 192 + h * 32 + row) * 128 + koff;
    *(bf16x8*)&Vs[row][koff] = *(const bf16x8*)src;
    *(bf16x8*)&Vs[row][koff + 8] = *(const bf16x8*)(src + 8);
  }
  int nrow = n0 + wid * 16 + lrow;
  bf16x8 qf = *(const bf16x8*)(q + ((long)b * NSEQ + nrow) * 192 + h * 32 + lk);
  __syncthreads();
  f32x4 zero = {0.f, 0.f, 0.f, 0.f};
  f32x4 s[8];
  // swapped: D[k][q] — lane's q-row = lrow (fixed), k = 16f + hi*4 + rr
  for (int f = 0; f < 8; f++) {
    bf16x8 kf = *(bf16x8*)&Ks[16 * f + lrow][lk];
    s[f] = MFMA16(kf, qf, zero);
  }
  float m = s[0][0];
  for (int f = 0; f < 8; f++) for (int rr = 0; rr < 4; rr++) m = fmaxf(m, s[f][rr]);
  m = fmaxf(m, __shfl_xor(m, 16));
  m = fmaxf(m, __shfl_xor(m, 32));
  float sum = 0.f;
  for (int f = 0; f < 8; f++) for (int rr = 0; rr < 4; rr++) {
    float p = __expf(s[f][rr] - m);
    s[f][rr] = p; sum += p;
  }
  sum += __shfl_xor(sum, 16);
  sum += __shfl_xor(sum, 32);
  float inv = 1.0f / sum;
  for (int f = 0; f < 8; f++) {
    bf16x4 pv;
    for (int rr = 0; rr < 4; rr++) pv[rr] = (bf16)(s[f][rr] * inv);
    *(bf16x4*)&Ps[wid][lrow][16 * f + hi * 4] = pv;
  }
  __syncthreads();
  f32x4 o[2];
  o[0] = zero; o[1] = zero;
  for (int ks = 0; ks < 4; ks++) {
    bf16x8 pf = *(bf16x8*)&Ps[wid][lrow][ks * 32 + lk];
    for (int j = 0; j < 2; j++) {
      bf16x8 vf = *(bf16x8*)&Vs[16 * j + lrow][ks * 32 + lk];
      o[j] = MFMA16(pf, vf, o[j]);
    }
  }
  for (int j = 0; j < 2; j++) for (int rr = 0; rr < 4; rr++) {
    int nn = n0 + wid * 16 + hi * 4 + rr;
    out_att[((long)b * NSEQ + nn) * 192 + h * 32 + 16 * j + lrow] = (bf16)o[j][rr];
  }
}

// ---------------- proj GEMM full-N: out(128 rows, all 192 cols) fp32; projw LDS-resident -----------
__launch_bounds__(256)
__global__ void k_proj(const bf16* __restrict__ oa, const bf16* __restrict__ projw,
                       const float* __restrict__ proj_b, float* __restrict__ out) {
  __shared__ bf16 As[128][104];
  __shared__ bf16 Bs[192][200];
  long g0 = (long)blockIdx.x * 128;
  int tid = threadIdx.x;
  int wid = tid >> 6, lane = tid & 63;
  int lrow = lane & 15, lk = (lane >> 4) * 8;
  {
    int koff = (tid & 3) * 48;
    for (int r0 = 0; r0 < 192; r0 += 64) {
      int row = r0 + (tid >> 2);
      const bf16* Bp = projw + (long)row * 192 + koff;
      for (int m = 0; m < 6; m++)
        *(bf16x8*)&Bs[row][koff + 8 * m] = *(const bf16x8*)(Bp + 8 * m);
    }
  }
  int arow = tid >> 1, half = tid & 1;
  const bf16* Ap = oa + (g0 + arow) * 192 + half * 48;
  f32x4 zero = {0.f, 0.f, 0.f, 0.f};
  f32x4 acc[2][12];
  for (int i = 0; i < 2; i++) for (int j = 0; j < 12; j++) acc[i][j] = zero;
  for (int k0 = 0; k0 < 192; k0 += 96) {
    for (int m = 0; m < 6; m++)
      *(bf16x8*)&As[arow][half * 48 + 8 * m] = *(const bf16x8*)(Ap + k0 + 8 * m);
    __syncthreads();
    for (int ks = 0; ks < 3; ks++) {
      bf16x8 af[2];
      for (int i = 0; i < 2; i++) af[i] = *(bf16x8*)&As[wid * 32 + 16 * i + lrow][ks * 32 + lk];
      for (int j = 0; j < 12; j++) {
        bf16x8 bv = *(bf16x8*)&Bs[16 * j + lrow][k0 + ks * 32 + lk];
        acc[0][j] = MFMA16(af[0], bv, acc[0][j]);
        acc[1][j] = MFMA16(af[1], bv, acc[1][j]);
      }
    }
    __syncthreads();
  }
  for (int i = 0; i < 2; i++) for (int j = 0; j < 12; j++) for (int rr = 0; rr < 4; rr++) {
    long grow = g0 + wid * 32 + 16 * i + (lane >> 4) * 4 + rr;
    int c = 16 * j + lrow;
    out[grow * 192 + c] = acc[i][j][rr] + proj_b[c];
  }
}

extern "C" void kernel_launch(void* const* d_in, const int* in_sizes, int n_in,
                              void* d_out, int out_size, void* d_ws, size_t ws_size,
                              hipStream_t stream) {
  const float* x      = (const float*)d_in[0];
  const float* qkv_w  = (const float*)d_in[1];
  const float* qkv_b  = (const float*)d_in[2];
  const float* E_w    = (const float*)d_in[3];
  const float* E_b    = (const float*)d_in[4];
  const float* F_w    = (const float*)d_in[5];
  const float* F_b    = (const float*)d_in[6];
  const float* proj_w = (const float*)d_in[7];
  const float* proj_b = (const float*)d_in[8];
  float* out = (float*)d_out;

  char* ws = (char*)d_ws;
  size_t off = 0;
  auto alloc = [&](size_t bytes) { char* p = ws + off; off += (bytes + 255) & ~(size_t)255; return p; };
  bf16* qkvw     = (bf16*)alloc((size_t)110592 * 2);
  bf16* EF       = (bf16*)alloc((size_t)802816 * 2);
  bf16* projw    = (bf16*)alloc((size_t)36864 * 2);
  float* rowsums = (float*)alloc((size_t)256 * 4);
  bf16* xmT      = (bf16*)alloc((size_t)32 * 192 * NSEQ * 2);   // reused as out_att after xlow
  float* partial = (float*)alloc((size_t)224 * 49152 * 4);      // 44 MB; aliased by q below
  bf16* q        = (bf16*)partial;                              // lifetimes disjoint (qgemm after reduce)
  bf16* el_fl    = (bf16*)alloc((size_t)32 * 256 * 192 * 2);
  bf16* k_low    = (bf16*)alloc((size_t)32 * 128 * 192 * 2);
  bf16* v_lowT   = (bf16*)alloc((size_t)32 * 192 * 128 * 2);
  bf16* out_att  = xmT;

  k_convert<<<dim3(480), dim3(256), 0, stream>>>(qkv_w, E_w, F_w, proj_w, qkvw, EF, projw);
  k_rowsum<<<dim3(256), dim3(256), 0, stream>>>(E_w, F_w, rowsums);
  k_xT<<<dim3(32 * 49), dim3(256), 0, stream>>>(x, xmT);
  k_xlow<<<dim3(224), dim3(512), 0, stream>>>(EF, xmT, partial);
  k_reduce<<<dim3(1536), dim3(256), 0, stream>>>(partial, el_fl);
  k_lowproj<<<dim3(384), dim3(256), 0, stream>>>(el_fl, qkvw, qkv_b, E_b, F_b, rowsums, k_low, v_lowT);
  k_qgemm2<<<dim3(784), dim3(256), 0, stream>>>(x, qkvw, qkv_b, q);
  k_attn<<<dim3(32 * 6 * 49), dim3(256), 0, stream>>>(q, k_low, v_lowT, out_att);
  k_proj<<<dim3(784), dim3(256), 0, stream>>>(out_att, projw, proj_b, out);
}

// Round 4
// 293.188 us; speedup vs baseline: 1.5992x; 1.0248x over previous
//
#include <hip/hip_runtime.h>

typedef __bf16 bf16;
typedef bf16 bf16x8 __attribute__((ext_vector_type(8)));
typedef bf16 bf16x4 __attribute__((ext_vector_type(4)));
typedef float f32x4 __attribute__((ext_vector_type(4)));

#define MFMA16(a,b,c) __builtin_amdgcn_mfma_f32_16x16x32_bf16(a,b,c,0,0,0)

#define NSEQ 3136
#define CDIM 192

__device__ inline bf16x8 cvt8(float4 a, float4 b) {
  bf16x8 r;
  r[0]=(bf16)a.x; r[1]=(bf16)a.y; r[2]=(bf16)a.z; r[3]=(bf16)a.w;
  r[4]=(bf16)b.x; r[5]=(bf16)b.y; r[6]=(bf16)b.z; r[7]=(bf16)b.w;
  return r;
}

__device__ inline bf16x4 cvt4(float4 a) {
  bf16x4 r;
  r[0]=(bf16)a.x; r[1]=(bf16)a.y; r[2]=(bf16)a.z; r[3]=(bf16)a.w;
  return r;
}

// ---------------- prep: rowsums (blocks 0..255) + weight convert (blocks 256..735) -----------------
__global__ void k_prep(const float* __restrict__ qkv_w, const float* __restrict__ E_w,
                       const float* __restrict__ F_w, const float* __restrict__ proj_w,
                       bf16* __restrict__ qkvw, bf16* __restrict__ EF, bf16* __restrict__ projw,
                       float* __restrict__ rowsums) {
  if (blockIdx.x < 256) {
    __shared__ float red[4];
    int row = blockIdx.x; // 0..255
    const float* src = (row < 128) ? (E_w + (long)row * NSEQ) : (F_w + (long)(row - 128) * NSEQ);
    float s = 0.f;
    for (int i = threadIdx.x; i < 784; i += 256) {
      float4 f = *(const float4*)(src + i * 4);
      s += f.x + f.y + f.z + f.w;
    }
    for (int off = 32; off; off >>= 1) s += __shfl_xor(s, off);
    if ((threadIdx.x & 63) == 0) red[threadIdx.x >> 6] = s;
    __syncthreads();
    if (threadIdx.x == 0) rowsums[row] = red[0] + red[1] + red[2] + red[3];
  } else {
    int i4 = (blockIdx.x - 256) * blockDim.x + threadIdx.x;
    const int tot4 = 950272 / 4;
    const int stride = 480 * 256;
    for (; i4 < tot4; i4 += stride) {
      int i = i4 * 4;
      float4 f;
      bf16* dst;
      if (i < 110592)      { f = *(const float4*)(qkv_w + i);            dst = qkvw + i; }
      else if (i < 512000) { f = *(const float4*)(E_w + (i - 110592));   dst = EF + (i - 110592); }
      else if (i < 913408) { f = *(const float4*)(F_w + (i - 512000));   dst = EF + (i - 110592); }
      else                 { f = *(const float4*)(proj_w + (i - 913408)); dst = projw + (i - 913408); }
      *(bf16x4*)dst = cvt4(f);
    }
  }
}

// ---------------- fused window_reverse+transpose + Q GEMM --------------------------------------
// x (2048,49,192) f32 -> xmT (32,192,3136) bf16  AND  q = (x@Wq^T + bq)*scale (bf16, xm row order)
// x read from HBM exactly once. tile 64x196 (25KB) + Wq half 192x104 (40KB) = 65KB -> 2 blk/CU.
__launch_bounds__(256)
__global__ void k_xTq(const float* __restrict__ x, const bf16* __restrict__ qkvw,
                      const float* __restrict__ qkv_b, bf16* __restrict__ xmT,
                      bf16* __restrict__ q) {
  __shared__ bf16 tile[64][196];
  __shared__ bf16 Bs[192][104];   // Wq K-half: row = out col c, 96 K entries
  int blk = blockIdx.x;
  int b = blk / 49, n0 = (blk % 49) * 64;
  int tid = threadIdx.x;
  int wid = tid >> 6, lane = tid & 63;
  int lrow = lane & 15, hi = lane >> 4, lk = hi * 8;
  // stage x tile (f32 -> bf16): 64 rows x 48 float4, 48 consecutive lanes per source row
  for (int e = tid; e < 3072; e += 256) {
    int row = e / 48, c4 = e % 48;
    int n = n0 + row;
    int r = n / 56, cc = n % 56;
    long srcrow = (long)(b * 64 + (r / 7) * 8 + (cc / 7)) * 49 + (r % 7) * 7 + (cc % 7);
    float4 f = *(const float4*)(x + srcrow * 192 + c4 * 4);
    *(bf16x4*)&tile[row][c4 * 4] = cvt4(f);
  }
  // stage Wq K-half 0 (k=0..95): 192 rows x 12 chunks of 8
  for (int u = tid; u < 2304; u += 256) {
    int row = u / 12, koff = (u % 12) * 8;
    *(bf16x8*)&Bs[row][koff] = *(const bf16x8*)(qkvw + (long)row * 192 + koff);
  }
  __syncthreads();
  f32x4 zero = {0.f, 0.f, 0.f, 0.f};
  f32x4 acc[12];
  for (int j = 0; j < 12; j++) acc[j] = zero;
  // MFMA half 0 (per wave: 16 output rows x 192 cols)
  for (int ks = 0; ks < 3; ks++) {
    bf16x8 af = *(bf16x8*)&tile[wid * 16 + lrow][ks * 32 + lk];
    for (int j = 0; j < 12; j++) {
      bf16x8 bv = *(bf16x8*)&Bs[16 * j + lrow][ks * 32 + lk];
      acc[j] = MFMA16(af, bv, acc[j]);
    }
  }
  // transpose writes: 192 c-rows x 8 chunks of 8 n; 8 consecutive threads -> 128B contiguous
  for (int e = tid; e < 1536; e += 256) {
    int c = e >> 3, k = e & 7;
    bf16x8 v;
    for (int jj = 0; jj < 8; jj++) v[jj] = tile[k * 8 + jj][c];
    *(bf16x8*)(xmT + ((long)b * 192 + c) * NSEQ + n0 + k * 8) = v;
  }
  __syncthreads();   // all Bs half-0 reads done
  // stage Wq K-half 1 (k=96..191)
  for (int u = tid; u < 2304; u += 256) {
    int row = u / 12, koff = (u % 12) * 8;
    *(bf16x8*)&Bs[row][koff] = *(const bf16x8*)(qkvw + (long)row * 192 + 96 + koff);
  }
  __syncthreads();
  for (int ks = 0; ks < 3; ks++) {
    bf16x8 af = *(bf16x8*)&tile[wid * 16 + lrow][96 + ks * 32 + lk];
    for (int j = 0; j < 12; j++) {
      bf16x8 bv = *(bf16x8*)&Bs[16 * j + lrow][ks * 32 + lk];
      acc[j] = MFMA16(af, bv, acc[j]);
    }
  }
  const float scale = 0.17677669529663687f; // 1/sqrt(32)
  for (int j = 0; j < 12; j++) for (int rr = 0; rr < 4; rr++) {
    int rl = wid * 16 + hi * 4 + rr;
    int c = 16 * j + lrow;
    float v = (acc[j][rr] + qkv_b[c]) * scale;
    q[((long)b * NSEQ + n0 + rl) * 192 + c] = (bf16)v;
  }
}

// ---------------- xlow GEMM: one block per (b, K-slice); full 256x192 tile, K=448 ------------------
__launch_bounds__(512)
__global__ void k_xlow(const bf16* __restrict__ EF, const bf16* __restrict__ xmT,
                       float* __restrict__ partial) {
  __shared__ bf16 As[256][72];
  __shared__ bf16 Bs[192][72];
  int idx = blockIdx.x;          // b*7 + s
  int s = idx % 7, b = idx / 7;
  int kbase = s * 448;
  int tid = threadIdx.x;
  int wid = tid >> 6, lane = tid & 63;
  int wm = wid >> 2, wn = wid & 3;        // 2 x 4 wave grid
  int lrow = lane & 15, hi = lane >> 4, lk = hi * 8;
  f32x4 zero = {0.f, 0.f, 0.f, 0.f};
  f32x4 acc[8][3];
  for (int i = 0; i < 8; i++) for (int j = 0; j < 3; j++) acc[i][j] = zero;
  for (int k0 = 0; k0 < 448; k0 += 64) {
    for (int i = 0; i < 4; i++) {
      int unit = i * 512 + tid;
      int row = unit >> 3, koff = (unit & 7) * 8;
      *(bf16x8*)&As[row][koff] = *(const bf16x8*)(EF + (long)row * NSEQ + kbase + k0 + koff);
    }
    for (int i = 0; i < 3; i++) {
      int unit = i * 512 + tid;
      int row = unit >> 3, koff = (unit & 7) * 8;
      *(bf16x8*)&Bs[row][koff] = *(const bf16x8*)(xmT + ((long)b * 192 + row) * NSEQ + kbase + k0 + koff);
    }
    __syncthreads();
    for (int ks = 0; ks < 2; ks++) {
      bf16x8 af[8], bfv[3];
      for (int i = 0; i < 8; i++) af[i]  = *(bf16x8*)&As[wm * 128 + 16 * i + lrow][ks * 32 + lk];
      for (int j = 0; j < 3; j++) bfv[j] = *(bf16x8*)&Bs[wn * 48 + 16 * j + lrow][ks * 32 + lk];
      for (int i = 0; i < 8; i++) for (int j = 0; j < 3; j++) acc[i][j] = MFMA16(af[i], bfv[j], acc[i][j]);
    }
    __syncthreads();
  }
  float* P = partial + (long)idx * 49152;  // 256 x 192 f32
  for (int i = 0; i < 8; i++) for (int j = 0; j < 3; j++) for (int rr = 0; rr < 4; rr++) {
    int rl = wm * 128 + 16 * i + hi * 4 + rr;
    int cl = wn * 48 + 16 * j + lrow;
    P[rl * 192 + cl] = acc[i][j][rr];
  }
}

// ---------------- reduce 7 split-K partials -> el_fl (b,256,192) bf16 (linear, vectorized) ---------
__global__ void k_reduce(const float* __restrict__ partial, bf16* __restrict__ el_fl) {
  int blk = blockIdx.x;          // 32 b x 48 chunks
  int b = blk / 48, ch = blk % 48;
  long e = (long)ch * 1024 + threadIdx.x * 4;   // 0..49151
  const float* P = partial + (long)b * 7 * 49152 + e;
  float4 sum = {0.f, 0.f, 0.f, 0.f};
  for (int s = 0; s < 7; s++) {
    float4 f = *(const float4*)(P + (long)s * 49152);
    sum.x += f.x; sum.y += f.y; sum.z += f.z; sum.w += f.w;
  }
  *(bf16x4*)(el_fl + (long)b * 49152 + e) = cvt4(sum);
}

// ---------------- low-rank proj: k_lowH = el@Wk^T + bias (HEAD-MAJOR) ; v_lowT = Wv@fl^T + bias ----
__launch_bounds__(256)
__global__ void k_lowproj(const bf16* __restrict__ el_fl, const bf16* __restrict__ qkvw,
                          const float* __restrict__ qkv_b, const float* __restrict__ E_b,
                          const float* __restrict__ F_b, const float* __restrict__ rowsums,
                          bf16* __restrict__ k_lowH, bf16* __restrict__ v_lowT) {
  __shared__ bf16 As[64][200];
  __shared__ bf16 Bs[64][200];
  int idx = blockIdx.x;
  int b = idx / 12, rem = idx % 12;
  int type = rem / 6; rem %= 6;
  int bm, bn;
  if (type == 0) { bm = rem / 3; bn = rem % 3; }
  else           { bm = rem / 2; bn = rem % 2; }
  int m0 = bm * 64, n0 = bn * 64;
  int tid = threadIdx.x;
  int wid = tid >> 6, lane = tid & 63;
  int wm = wid >> 1, wn = wid & 1;
  int lrow = lane & 15, lk = (lane >> 4) * 8;
  int srow = tid >> 2, skoff = (tid & 3) * 16;
  const bf16* Ap; const bf16* Bp;
  if (type == 0) {
    Ap = el_fl + ((long)b * 256 + m0 + srow) * 192 + skoff;
    Bp = qkvw + (long)(192 + n0 + srow) * 192 + skoff;
  } else {
    Ap = qkvw + (long)(384 + m0 + srow) * 192 + skoff;
    Bp = el_fl + ((long)b * 256 + 128 + n0 + srow) * 192 + skoff;
  }
  for (int kk = 0; kk < 192; kk += 64) {
    *(bf16x8*)&As[srow][kk + skoff]     = *(const bf16x8*)(Ap + kk);
    *(bf16x8*)&As[srow][kk + skoff + 8] = *(const bf16x8*)(Ap + kk + 8);
    *(bf16x8*)&Bs[srow][kk + skoff]     = *(const bf16x8*)(Bp + kk);
    *(bf16x8*)&Bs[srow][kk + skoff + 8] = *(const bf16x8*)(Bp + kk + 8);
  }
  __syncthreads();
  f32x4 zero = {0.f, 0.f, 0.f, 0.f};
  f32x4 acc[2][2];
  for (int i = 0; i < 2; i++) for (int j = 0; j < 2; j++) acc[i][j] = zero;
  for (int ks = 0; ks < 6; ks++) {
    bf16x8 af[2], bfv[2];
    for (int i = 0; i < 2; i++) af[i]  = *(bf16x8*)&As[wm * 32 + 16 * i + lrow][ks * 32 + lk];
    for (int j = 0; j < 2; j++) bfv[j] = *(bf16x8*)&Bs[wn * 32 + 16 * j + lrow][ks * 32 + lk];
    for (int i = 0; i < 2; i++) for (int j = 0; j < 2; j++) acc[i][j] = MFMA16(af[i], bfv[j], acc[i][j]);
  }
  if (type == 0) {
    for (int i = 0; i < 2; i++) for (int j = 0; j < 2; j++) for (int rr = 0; rr < 4; rr++) {
      int kr = m0 + wm * 32 + 16 * i + (lane >> 4) * 4 + rr;
      int c = n0 + wn * 32 + 16 * j + lrow;
      float v = acc[i][j][rr] + rowsums[kr] * qkv_b[192 + c] + E_b[kr];
      // head-major: [b][h][128][32]
      k_lowH[(((long)b * 6 + (c >> 5)) * 128 + kr) * 32 + (c & 31)] = (bf16)v;
    }
  } else {
    for (int i = 0; i < 2; i++) for (int j = 0; j < 2; j++) for (int rr = 0; rr < 4; rr++) {
      int c = m0 + wm * 32 + 16 * i + (lane >> 4) * 4 + rr;
      int kr = n0 + wn * 32 + 16 * j + lrow;
      float v = acc[i][j][rr] + rowsums[128 + kr] * qkv_b[384 + c] + F_b[kr];
      v_lowT[((long)b * 192 + c) * 128 + kr] = (bf16)v;
    }
  }
}

// ---------------- fused attention: swapped QK^T -> in-register softmax -----------------------------
__launch_bounds__(256)
__global__ void k_attn(const bf16* __restrict__ q, const bf16* __restrict__ k_lowH,
                       const bf16* __restrict__ v_lowT, bf16* __restrict__ out_att) {
  __shared__ bf16 Ks[128][40];
  __shared__ bf16 Vs[32][136];
  __shared__ bf16 Ps[4][16][136];
  int idx = blockIdx.x;
  int nt = idx % 49, bh = idx / 49;
  int h = bh % 6, b = bh / 6;
  int n0 = nt * 64;
  int tid = threadIdx.x;
  int wid = tid >> 6, lane = tid & 63;
  int lrow = lane & 15, hi = lane >> 4, lk = hi * 8;
  {
    // head-major K: fully contiguous 8KB block
    int row = tid >> 1, koff = (tid & 1) * 16;
    const bf16* src = k_lowH + (((long)b * 6 + h) * 128 + row) * 32 + koff;
    *(bf16x8*)&Ks[row][koff] = *(const bf16x8*)src;
    *(bf16x8*)&Ks[row][koff + 8] = *(const bf16x8*)(src + 8);
  }
  {
    int row = tid >> 3, koff = (tid & 7) * 16;
    const bf16* src = v_lowT + ((long)b * 192 + h * 32 + row) * 128 + koff;
    *(bf16x8*)&Vs[row][koff] = *(const bf16x8*)src;
    *(bf16x8*)&Vs[row][koff + 8] = *(const bf16x8*)(src + 8);
  }
  int nrow = n0 + wid * 16 + lrow;
  bf16x8 qf = *(const bf16x8*)(q + ((long)b * NSEQ + nrow) * 192 + h * 32 + lk);
  __syncthreads();
  f32x4 zero = {0.f, 0.f, 0.f, 0.f};
  f32x4 s[8];
  // swapped: D[k][q] — lane's q-row = lrow (fixed), k = 16f + hi*4 + rr
  for (int f = 0; f < 8; f++) {
    bf16x8 kf = *(bf16x8*)&Ks[16 * f + lrow][lk];
    s[f] = MFMA16(kf, qf, zero);
  }
  float m = s[0][0];
  for (int f = 0; f < 8; f++) for (int rr = 0; rr < 4; rr++) m = fmaxf(m, s[f][rr]);
  m = fmaxf(m, __shfl_xor(m, 16));
  m = fmaxf(m, __shfl_xor(m, 32));
  float sum = 0.f;
  for (int f = 0; f < 8; f++) for (int rr = 0; rr < 4; rr++) {
    float p = __expf(s[f][rr] - m);
    s[f][rr] = p; sum += p;
  }
  sum += __shfl_xor(sum, 16);
  sum += __shfl_xor(sum, 32);
  float inv = 1.0f / sum;
  for (int f = 0; f < 8; f++) {
    bf16x4 pv;
    for (int rr = 0; rr < 4; rr++) pv[rr] = (bf16)(s[f][rr] * inv);
    *(bf16x4*)&Ps[wid][lrow][16 * f + hi * 4] = pv;
  }
  __syncthreads();
  f32x4 o[2];
  o[0] = zero; o[1] = zero;
  for (int ks = 0; ks < 4; ks++) {
    bf16x8 pf = *(bf16x8*)&Ps[wid][lrow][ks * 32 + lk];
    for (int j = 0; j < 2; j++) {
      bf16x8 vf = *(bf16x8*)&Vs[16 * j + lrow][ks * 32 + lk];
      o[j] = MFMA16(pf, vf, o[j]);
    }
  }
  for (int j = 0; j < 2; j++) for (int rr = 0; rr < 4; rr++) {
    int nn = n0 + wid * 16 + hi * 4 + rr;
    out_att[((long)b * NSEQ + nn) * 192 + h * 32 + 16 * j + lrow] = (bf16)o[j][rr];
  }
}

// ---------------- proj GEMM full-N: out(128 rows, all 192 cols) fp32; projw LDS-resident -----------
__launch_bounds__(256)
__global__ void k_proj(const bf16* __restrict__ oa, const bf16* __restrict__ projw,
                       const float* __restrict__ proj_b, float* __restrict__ out) {
  __shared__ bf16 As[128][104];
  __shared__ bf16 Bs[192][200];
  long g0 = (long)blockIdx.x * 128;
  int tid = threadIdx.x;
  int wid = tid >> 6, lane = tid & 63;
  int lrow = lane & 15, lk = (lane >> 4) * 8;
  {
    int koff = (tid & 3) * 48;
    for (int r0 = 0; r0 < 192; r0 += 64) {
      int row = r0 + (tid >> 2);
      const bf16* Bp = projw + (long)row * 192 + koff;
      for (int m = 0; m < 6; m++)
        *(bf16x8*)&Bs[row][koff + 8 * m] = *(const bf16x8*)(Bp + 8 * m);
    }
  }
  int arow = tid >> 1, half = tid & 1;
  const bf16* Ap = oa + (g0 + arow) * 192 + half * 48;
  f32x4 zero = {0.f, 0.f, 0.f, 0.f};
  f32x4 acc[2][12];
  for (int i = 0; i < 2; i++) for (int j = 0; j < 12; j++) acc[i][j] = zero;
  for (int k0 = 0; k0 < 192; k0 += 96) {
    for (int m = 0; m < 6; m++)
      *(bf16x8*)&As[arow][half * 48 + 8 * m] = *(const bf16x8*)(Ap + k0 + 8 * m);
    __syncthreads();
    for (int ks = 0; ks < 3; ks++) {
      bf16x8 af[2];
      for (int i = 0; i < 2; i++) af[i] = *(bf16x8*)&As[wid * 32 + 16 * i + lrow][ks * 32 + lk];
      for (int j = 0; j < 12; j++) {
        bf16x8 bv = *(bf16x8*)&Bs[16 * j + lrow][k0 + ks * 32 + lk];
        acc[0][j] = MFMA16(af[0], bv, acc[0][j]);
        acc[1][j] = MFMA16(af[1], bv, acc[1][j]);
      }
    }
    __syncthreads();
  }
  for (int i = 0; i < 2; i++) for (int j = 0; j < 12; j++) for (int rr = 0; rr < 4; rr++) {
    long grow = g0 + wid * 32 + 16 * i + (lane >> 4) * 4 + rr;
    int c = 16 * j + lrow;
    out[grow * 192 + c] = acc[i][j][rr] + proj_b[c];
  }
}

extern "C" void kernel_launch(void* const* d_in, const int* in_sizes, int n_in,
                              void* d_out, int out_size, void* d_ws, size_t ws_size,
                              hipStream_t stream) {
  const float* x      = (const float*)d_in[0];
  const float* qkv_w  = (const float*)d_in[1];
  const float* qkv_b  = (const float*)d_in[2];
  const float* E_w    = (const float*)d_in[3];
  const float* E_b    = (const float*)d_in[4];
  const float* F_w    = (const float*)d_in[5];
  const float* F_b    = (const float*)d_in[6];
  const float* proj_w = (const float*)d_in[7];
  const float* proj_b = (const float*)d_in[8];
  float* out = (float*)d_out;

  char* ws = (char*)d_ws;
  size_t off = 0;
  auto alloc = [&](size_t bytes) { char* p = ws + off; off += (bytes + 255) & ~(size_t)255; return p; };
  bf16* qkvw     = (bf16*)alloc((size_t)110592 * 2);
  bf16* EF       = (bf16*)alloc((size_t)802816 * 2);
  bf16* projw    = (bf16*)alloc((size_t)36864 * 2);
  float* rowsums = (float*)alloc((size_t)256 * 4);
  bf16* xmT      = (bf16*)alloc((size_t)32 * 192 * NSEQ * 2);   // reused as out_att after xlow
  bf16* q        = (bf16*)alloc((size_t)32 * NSEQ * 192 * 2);   // live xTq -> attn (no alias)
  float* partial = (float*)alloc((size_t)224 * 49152 * 4);      // 44 MB
  bf16* el_fl    = (bf16*)alloc((size_t)32 * 256 * 192 * 2);
  bf16* k_lowH   = (bf16*)alloc((size_t)32 * 6 * 128 * 32 * 2);
  bf16* v_lowT   = (bf16*)alloc((size_t)32 * 192 * 128 * 2);
  bf16* out_att  = xmT;

  k_prep<<<dim3(736), dim3(256), 0, stream>>>(qkv_w, E_w, F_w, proj_w, qkvw, EF, projw, rowsums);
  k_xTq<<<dim3(32 * 49), dim3(256), 0, stream>>>(x, qkvw, qkv_b, xmT, q);
  k_xlow<<<dim3(224), dim3(512), 0, stream>>>(EF, xmT, partial);
  k_reduce<<<dim3(1536), dim3(256), 0, stream>>>(partial, el_fl);
  k_lowproj<<<dim3(384), dim3(256), 0, stream>>>(el_fl, qkvw, qkv_b, E_b, F_b, rowsums, k_lowH, v_lowT);
  k_attn<<<dim3(32 * 6 * 49), dim3(256), 0, stream>>>(q, k_lowH, v_lowT, out_att);
  k_proj<<<dim3(784), dim3(256), 0, stream>>>(out_att, projw, proj_b, out);
}